// Round 9
// baseline (109.243 us; speedup 1.0000x reference)
//
#include <hip/hip_runtime.h>

// Beam-search gather_tree v3: decoupled map-build + pure-VALU chain walk.
// [max_len=256, batch=4096, beam=8] int32 -> ids [4096,8,256] + lengths [4096,8].
//
// Block = 1024 threads (16 waves) owns 64 chains (8 batches x 8 beams);
// wave w owns t-segment [16w,16w+16). Grid 512 -> 2 blocks/CU, 32 waves/CU.
//
// A1: parent maps are chain-state-independent -> int4 loads (1 instr = 4
//     t-rows x 64 chains), pack 4x3-bit parents, shfl_xor(1) merges halves,
//     store 24-bit map/(t,batch) to LDS maps[256][8]. No bpermute chain.
// A2: segment exit map F_w by walking 8 hypotheses (lane=(b,h)) in PURE VALU:
//     cur=(m>>3cur)&7. No history stored.
// C1: entry state = compose higher segmaps; re-walk own segment: dense
//     own-chain token load (hoistable) + 1 shfl gather + VALU map step;
//     resolved tokens -> tile2[chain][t] (PITCH 257: 2-way banks both phases).
// C2: first_end = min over segments (= lengths); transpose write, 256B
//     coalesced dword stores.

constexpr int MAX_LEN = 256;
constexpr int BATCH   = 4096;
constexpr int BEAM    = 8;
constexpr int NCHAIN  = BATCH * BEAM;   // 32768
constexpr int NW      = 16;             // waves per block
constexpr int SEG     = 16;             // t-steps per segment
constexpr int TP      = 257;            // tile2 pitch (odd -> 2-way banks)
constexpr unsigned ID_MAP = 0xFAC688u;  // identity 8->8 map (field j = j)

__global__ __launch_bounds__(1024, 8)
void gather_tree_kernel(const int* __restrict__ step_ids,
                        const int* __restrict__ parent_ids,
                        const int* __restrict__ seq_lens,
                        const int* __restrict__ end_id_p,
                        int* __restrict__ out_ids,
                        int* __restrict__ out_lens)
{
    __shared__ int      tile2[64 * TP];     // 65,792 B: resolved tokens [chain][t]
    __shared__ unsigned maps[MAX_LEN * 8];  //  8,192 B: 24-bit parent map [t][b_loc]
    __shared__ unsigned segmap[NW * 8];     //    512 B: per-segment exit map
    __shared__ int      fe_buf[NW * 64];    //  4,096 B: per-segment first_end
    // total 78,592 B -> 2 blocks/CU = 32 waves/CU

    const int tid   = threadIdx.x;
    const int w     = tid >> 6;          // wave id == segment id, 0..15
    const int lane  = tid & 63;
    const int b_loc = lane >> 3;         // batch within block, 0..7
    const int h     = lane & 7;          // hypothesis / own beam
    const int bj0   = blockIdx.x * 64;   // first chain of this block
    const int tbase = w * SEG;
    const int end_tok = *end_id_p;

    // msl = min(max over beams of seq_lens[b], MAX_LEN), uniform per 8-lane group
    int sl = seq_lens[bj0 + lane];
    sl = max(sl, __shfl_xor(sl, 1));
    sl = max(sl, __shfl_xor(sl, 2));
    sl = max(sl, __shfl_xor(sl, 4));
    const int msl = min(sl, MAX_LEN);

    // ---------------- A1: build packed parent maps (int4 loads) ----------------
    // lane: t_sub = lane>>4 (0..3), q = lane&15 -> chains 4q..4q+3 of this block
    {
        const int t_sub = lane >> 4;
        const int q     = lane & 15;
        const int4* p4  = (const int4*)parent_ids;   // 16B-aligned: NCHAIN%4==0
        #pragma unroll
        for (int k = 0; k < SEG; k += 4) {
            const int t = tbase + k + t_sub;
            int4 p = p4[t * (NCHAIN / 4) + (bj0 >> 2) + q];   // 1KB/wave, dense
            unsigned mm = (unsigned)(p.x & 7)        | ((unsigned)(p.y & 7) << 3)
                        | ((unsigned)(p.z & 7) << 6) | ((unsigned)(p.w & 7) << 9);
            unsigned oo = (unsigned)__shfl_xor((int)mm, 1);   // other half of batch
            if ((q & 1) == 0)
                maps[t * 8 + (q >> 1)] = mm | (oo << 12);     // 32 consec dwords: conflict-free
        }
    }
    // wave reads back only its own writes -> no barrier needed before A2

    // ---------------- A2: segment exit map, pure-VALU hypothesis walk ----------------
    int cur = h;
    #pragma unroll
    for (int i = SEG - 1; i >= 0; --i) {
        const int t = tbase + i;
        const unsigned m = (t < msl) ? maps[t * 8 + b_loc] : ID_MAP;
        cur = (m >> (3 * cur)) & 7;                           // 2 VALU ops
    }
    unsigned fm = (unsigned)cur << (3 * h);
    fm |= (unsigned)__shfl_xor((int)fm, 1);
    fm |= (unsigned)__shfl_xor((int)fm, 2);
    fm |= (unsigned)__shfl_xor((int)fm, 4);
    if (h == 0) segmap[w * 8 + b_loc] = fm;

    __syncthreads();

    // ---------------- C1: compose entry state, resolve own segment ----------------
    // entry state of chain j=h into segment w = F_{w+1}(F_{w+2}(...F_15(h)))
    int e = h;
    for (int ww = NW - 1; ww > w; --ww)
        e = (segmap[ww * 8 + b_loc] >> (3 * e)) & 7;

    int fe = MAX_LEN;
    int c2 = e;
    #pragma unroll
    for (int i = SEG - 1; i >= 0; --i) {
        const int t = tbase + i;
        const int tok_own = step_ids[t * NCHAIN + bj0 + lane];  // dense, chain-independent -> hoisted
        const int tokg = __shfl(tok_own, b_loc * 8 + c2);       // gather [b, cur]
        const unsigned m = (t < msl) ? maps[t * 8 + b_loc] : ID_MAP;
        const int tok = (t < msl) ? tokg : end_tok;
        if (tok == end_tok) fe = min(fe, t);
        tile2[lane * TP + t] = tok;                             // bank (lane+t)%32: 2-way
        c2 = (m >> (3 * c2)) & 7;
    }
    fe_buf[w * 64 + lane] = fe;

    __syncthreads();

    // ---------------- C2: lengths + transpose write ----------------
    int feg = fe_buf[lane];
    #pragma unroll
    for (int w2 = 1; w2 < NW; ++w2) feg = min(feg, fe_buf[w2 * 64 + lane]);
    if (w == 0) out_lens[bj0 + lane] = feg;                     // lengths == first_end

    // wave w writes chains [4w,4w+4): per chain, lanes cover t (256B coalesced)
    #pragma unroll
    for (int cc = 0; cc < 4; ++cc) {
        const int c = w * 4 + cc;
        const int fec = __shfl(feg, c);                         // uniform -> readlane
        #pragma unroll
        for (int k = 0; k < 4; ++k) {
            const int t = k * 64 + lane;
            const int v = tile2[c * TP + t];                    // bank (c+t+lane)%32: 2-way
            out_ids[(bj0 + c) * MAX_LEN + t] = (t < fec) ? v : end_tok;
        }
    }
}

extern "C" void kernel_launch(void* const* d_in, const int* in_sizes, int n_in,
                              void* d_out, int out_size, void* d_ws, size_t ws_size,
                              hipStream_t stream)
{
    const int* step_ids   = (const int*)d_in[0];  // output_ids [256,4096,8]
    const int* parent_ids = (const int*)d_in[1];  // parent_ids [256,4096,8]
    const int* seq_lens   = (const int*)d_in[2];  // out_seq_lens [4096,8]
    const int* end_id     = (const int*)d_in[3];  // scalar end_id

    int* out_ids  = (int*)d_out;                          // [4096,8,256]
    int* out_lens = (int*)d_out + MAX_LEN * NCHAIN;       // [4096,8]

    gather_tree_kernel<<<NCHAIN / 64, 1024, 0, stream>>>(
        step_ids, parent_ids, seq_lens, end_id, out_ids, out_lens);
}

// Round 10
// 107.410 us; speedup vs baseline: 1.0171x; 1.0171x over previous
//
#include <hip/hip_runtime.h>

// Beam-search gather_tree v4 = v2 skeleton + vectorized loads + VALU walk.
// [max_len=256, batch=4096, beam=8] int32 -> ids [4096,8,256] + lengths [4096,8].
//
// Block = 1024 threads (16 waves) owns 64 chains (8 batches x 8 beams);
// wave w owns t-segment [16w,16w+16). Grid 512 -> 2 blocks/CU, 32 waves/CU.
//
// Phase A (one pass over BOTH arrays, v2's schedule): int4 loads (8 VMEM
// instrs/wave vs v2's 32 scalar dwords); tokens staged to s_tile[t][chain]
// (PITCH 65, all-distinct banks on writes); parent maps packed in-register
// (shfl_xor(1) merges batch halves) into LDS maps[t][b] (conflict-free).
// Phase A2: segment exit map via pure-VALU hypothesis walk over maps
// (replaces v2's 16-deep serial ds_bpermute chain).
// Phase C1: entry state = compose higher segmaps; re-walk own segment from
// maps (VALU chain + pipelined LDS reads); gather tokens from s_tile;
// in-place resolve (descending t writes only rows above later reads).
// Phase C2: first_end min over segments (= lengths); transpose write,
// 256B coalesced dword stores. LDS 79,360 B = v2-identical.

constexpr int MAX_LEN = 256;
constexpr int BATCH   = 4096;
constexpr int BEAM    = 8;
constexpr int NCHAIN  = BATCH * BEAM;   // 32768
constexpr int PITCH   = 65;             // s_tile pitch (odd -> 2-way banks max)
constexpr int NW      = 16;             // waves per block
constexpr int SEG     = 16;             // t-steps per segment
constexpr unsigned ID_MAP = 0xFAC688u;  // identity 8->8 map (field j = j)

__global__ __launch_bounds__(1024, 8)
void gather_tree_kernel(const int* __restrict__ step_ids,
                        const int* __restrict__ parent_ids,
                        const int* __restrict__ seq_lens,
                        const int* __restrict__ end_id_p,
                        int* __restrict__ out_ids,
                        int* __restrict__ out_lens)
{
    __shared__ int      s_tile[MAX_LEN * PITCH]; // 66,560 B: raw then resolved tokens
    __shared__ unsigned maps[MAX_LEN * 8];       //  8,192 B: 24-bit parent map [t][b_loc]
    __shared__ unsigned segmap[NW * 8];          //    512 B: per-segment exit map
    __shared__ int      fe_buf[NW * 64];         //  4,096 B: per-segment first_end
    // total 79,360 B -> 2 blocks/CU = 32 waves/CU

    const int tid   = threadIdx.x;
    const int w     = tid >> 6;          // wave id == segment id, 0..15
    const int lane  = tid & 63;
    const int b_loc = lane >> 3;         // batch within block, 0..7
    const int h     = lane & 7;          // hypothesis / own beam
    const int bj0   = blockIdx.x * 64;   // first chain of this block
    const int tbase = w * SEG;
    const int end_tok = *end_id_p;

    // msl = min(max over beams of seq_lens[b], MAX_LEN), uniform per 8-lane group
    int sl = seq_lens[bj0 + lane];
    sl = max(sl, __shfl_xor(sl, 1));
    sl = max(sl, __shfl_xor(sl, 2));
    sl = max(sl, __shfl_xor(sl, 4));
    const int msl = min(sl, MAX_LEN);

    // ------ A1: int4 load both arrays; stage tokens; build packed maps ------
    // lane -> (t_sub = lane>>4 in 0..3, q = lane&15 -> chains 4q..4q+3)
    {
        const int t_sub = lane >> 4;
        const int q     = lane & 15;
        const int4* p4  = (const int4*)parent_ids;   // NCHAIN%4==0: aligned
        const int4* s4  = (const int4*)step_ids;
        #pragma unroll
        for (int k = 0; k < 4; ++k) {
            const int t  = tbase + k * 4 + t_sub;
            const int gi = t * (NCHAIN / 4) + (bj0 >> 2) + q;   // dense 1KB/wave
            const int4 pp = p4[gi];
            const int4 ss = s4[gi];
            const int base = t * PITCH + 4 * q;      // banks t_sub+4q+j: all distinct
            s_tile[base + 0] = ss.x;
            s_tile[base + 1] = ss.y;
            s_tile[base + 2] = ss.z;
            s_tile[base + 3] = ss.w;
            unsigned mm = (unsigned)(pp.x & 7)        | ((unsigned)(pp.y & 7) << 3)
                        | ((unsigned)(pp.z & 7) << 6) | ((unsigned)(pp.w & 7) << 9);
            const unsigned oo = (unsigned)__shfl_xor((int)mm, 1);  // other batch half
            if (!(q & 1))
                maps[t * 8 + (q >> 1)] = mm | (oo << 12);   // banks 8t_sub+q/2: distinct
        }
    }
    // same-wave LDS dependency A1->A2 handled by compiler lgkmcnt (no barrier)

    // ------ A2: segment exit map, pure-VALU hypothesis walk ------
    int cur = h;
    #pragma unroll
    for (int i = SEG - 1; i >= 0; --i) {
        const int t = tbase + i;
        const unsigned m = (t < msl) ? maps[t * 8 + b_loc] : ID_MAP;
        cur = (m >> (3 * cur)) & 7;                  // 2 VALU ops
    }
    unsigned fm = (unsigned)cur << (3 * h);
    fm |= (unsigned)__shfl_xor((int)fm, 1);
    fm |= (unsigned)__shfl_xor((int)fm, 2);
    fm |= (unsigned)__shfl_xor((int)fm, 4);
    if (h == 0) segmap[w * 8 + b_loc] = fm;

    __syncthreads();

    // ------ C1: compose entry state; re-walk own segment; resolve in place ------
    int e = h;
    for (int ww = NW - 1; ww > w; --ww)
        e = (segmap[ww * 8 + b_loc] >> (3 * e)) & 7;

    int fe = MAX_LEN;
    int c2 = e;                                      // state BEFORE step t (descending)
    #pragma unroll
    for (int i = SEG - 1; i >= 0; --i) {
        const int t = tbase + i;
        const unsigned m = (t < msl) ? maps[t * 8 + b_loc] : ID_MAP;
        int tok = s_tile[t * PITCH + b_loc * 8 + c2];   // gather [b, cur]; <=2-way banks
        tok = (t < msl) ? tok : end_tok;
        if (tok == end_tok) fe = min(fe, t);
        s_tile[t * PITCH + lane] = tok;              // in-place: row t wave-exclusive;
        c2 = (m >> (3 * c2)) & 7;                    // later iters only touch rows < t
    }
    fe_buf[w * 64 + lane] = fe;

    __syncthreads();

    // ------ C2: lengths + transpose write ------
    int feg = fe_buf[lane];
    #pragma unroll
    for (int w2 = 1; w2 < NW; ++w2) feg = min(feg, fe_buf[w2 * 64 + lane]);
    if (w == 0) out_lens[bj0 + lane] = feg;          // lengths == first_end

    // wave w writes chains [4w,4w+4): per chain, lanes cover t (256B coalesced)
    #pragma unroll
    for (int cc = 0; cc < 4; ++cc) {
        const int c = w * 4 + cc;
        const int fec = __shfl(feg, c);              // uniform src -> readlane
        #pragma unroll
        for (int k = 0; k < 4; ++k) {
            const int t = k * 64 + lane;
            const int v = s_tile[t * PITCH + c];     // stride-65 rows: 2-way max
            out_ids[(bj0 + c) * MAX_LEN + t] = (t < fec) ? v : end_tok;
        }
    }
}

extern "C" void kernel_launch(void* const* d_in, const int* in_sizes, int n_in,
                              void* d_out, int out_size, void* d_ws, size_t ws_size,
                              hipStream_t stream)
{
    const int* step_ids   = (const int*)d_in[0];  // output_ids [256,4096,8]
    const int* parent_ids = (const int*)d_in[1];  // parent_ids [256,4096,8]
    const int* seq_lens   = (const int*)d_in[2];  // out_seq_lens [4096,8]
    const int* end_id     = (const int*)d_in[3];  // scalar end_id

    int* out_ids  = (int*)d_out;                          // [4096,8,256]
    int* out_lens = (int*)d_out + MAX_LEN * NCHAIN;       // [4096,8]

    gather_tree_kernel<<<NCHAIN / 64, 1024, 0, stream>>>(
        step_ids, parent_ids, seq_lens, end_id, out_ids, out_lens);
}